// Round 2
// 820.450 us; speedup vs baseline: 1.0554x; 1.0554x over previous
//
#include <hip/hip_runtime.h>

#define B_   8
#define C_   64
#define O_   64
#define H_   512
#define Wd_  512
#define SEG_ 4
#define HS_  128   // H / SEG
#define WS_  128   // Wd / SEG

// Native clang vector type: __builtin_nontemporal_{load,store} requires a
// pointer to scalar/native-vector, not HIP's float4 class.
typedef float v4f __attribute__((ext_vector_type(4)));

// ---------------------------------------------------------------------------
// Kernel 1: segment mean-pool.
// Grid: B*C*SEG blocks; block (b,c,i) reduces rows [i*128, i*128+128) of the
// (b,c) 512x512 channel image (a contiguous 128*512-float region) into 4
// column-segment sums. With float4 loads and a stride-256 loop, (f & 127) is
// per-thread invariant => each thread's column segment j is FIXED, so one
// accumulator per thread suffices.
// x is streamed exactly once -> non-temporal loads (no reuse, keep L2 clean).
// ---------------------------------------------------------------------------
__global__ __launch_bounds__(256) void pool_kernel(const float* __restrict__ x,
                                                   float* __restrict__ pooled) {
    const int blk = blockIdx.x;      // ((b*C + c)*SEG + i)
    const int i   = blk & 3;
    const int bc  = blk >> 2;        // b*C + c
    const v4f* base =
        (const v4f*)(x + ((size_t)bc * H_ + (size_t)i * HS_) * Wd_);

    const int tid = threadIdx.x;
    float sum = 0.f;
    // 128*512/4 = 16384 float4s, 64 per thread
    #pragma unroll 8
    for (int f = tid; f < HS_ * Wd_ / 4; f += 256) {
        v4f v = __builtin_nontemporal_load(&base[f]);
        sum += (v.x + v.y) + (v.z + v.w);
    }

    // j = ((f*4) & 511) >> 7 = (tid & 127) >> 5 : constant per thread.
    // Reduce within each 32-lane group (all share the same j).
    for (int off = 16; off >= 1; off >>= 1)
        sum += __shfl_down(sum, off, 32);

    __shared__ float sums[8];        // 8 groups of 32; group g has j = g & 3
    const int g = tid >> 5;
    if ((tid & 31) == 0) sums[g] = sum;
    __syncthreads();

    if (tid < 4) {
        float total = sums[tid] + sums[tid + 4];   // groups g and g+4 share j
        pooled[(size_t)blk * 4 + tid] = total * (1.0f / (HS_ * WS_));
    }
}

// ---------------------------------------------------------------------------
// Kernel 2 (fused linear + broadcast).
// Grid: B*O*SEG blocks; block (b,o,i) first computes its own 4 tile values
//   t[j] = (sum_c pooled[b][c][i][j] * W[o][c] + bias[o]) * seg_w[i][j]
// wave-parallel (wave w owns j=w, lane l owns c=l; shfl tree-reduce), then
// fills rows [i*128, i*128+128) of the (b,o) output image.
// pooled (32 KiB) and W (16 KiB) are re-read by all 2048 blocks -> leave them
// cached; out is streamed once -> non-temporal stores.
// ---------------------------------------------------------------------------
__global__ __launch_bounds__(256) void linear_bcast_kernel(
        const float* __restrict__ pooled,
        const float* __restrict__ Wm,
        const float* __restrict__ bias,
        const float* __restrict__ seg_w,
        float* __restrict__ out) {
    const int blk = blockIdx.x;      // ((b*O + o)*SEG + i)
    const int i   = blk & 3;
    const int bo  = blk >> 2;        // b*O + o
    const int o   = bo & (O_ - 1);
    const int b   = bo >> 6;

    const int tid  = threadIdx.x;
    const int wave = tid >> 6;       // j = wave (4 waves, SEG = 4)
    const int lane = tid & 63;       // c = lane (C = 64 = wavefront size)

    // partial = pooled[b][c][i][j] * W[o][c]
    float partial = pooled[(size_t)b * C_ * 16 + lane * 16 + i * 4 + wave]
                  * Wm[(size_t)o * C_ + lane];
    #pragma unroll
    for (int off = 32; off >= 1; off >>= 1)
        partial += __shfl_down(partial, off, 64);

    __shared__ float tile[4];
    if (lane == 0)
        tile[wave] = (partial + bias[o]) * seg_w[i * 4 + wave];
    __syncthreads();

    // Same (tid & 127) invariance as before: each thread's column segment j
    // is fixed => value is uniform per thread; 64 coalesced float4 stores.
    const float v = tile[(tid & 127) >> 5];
    v4f vv;
    vv.x = v; vv.y = v; vv.z = v; vv.w = v;

    v4f* base = (v4f*)(out + ((size_t)bo * H_ + (size_t)i * HS_) * Wd_);
    #pragma unroll 8
    for (int f = tid; f < HS_ * Wd_ / 4; f += 256)
        __builtin_nontemporal_store(vv, &base[f]);
}

extern "C" void kernel_launch(void* const* d_in, const int* in_sizes, int n_in,
                              void* d_out, int out_size, void* d_ws, size_t ws_size,
                              hipStream_t stream) {
    const float* x     = (const float*)d_in[0];
    const float* Wm    = (const float*)d_in[1];
    const float* bias  = (const float*)d_in[2];
    const float* seg_w = (const float*)d_in[3];
    float* out = (float*)d_out;

    float* pooled = (float*)d_ws;    // B*C*16 = 8192 floats (32 KiB)

    pool_kernel<<<B_ * C_ * SEG_, 256, 0, stream>>>(x, pooled);
    linear_bcast_kernel<<<B_ * O_ * SEG_, 256, 0, stream>>>(
        pooled, Wm, bias, seg_w, out);
}